// Round 3
// baseline (376.993 us; speedup 1.0000x reference)
//
#include <hip/hip_runtime.h>

// Problem constants: codes [16,128,128,128] f32, segmap [16,4,1,256,256] i32,
// fc_w [512,128] f32, fc_b [512] f32.  Nearest 256->128 == sample (2y,2x).
#define B    16
#define S    4
#define F    128
#define HW   16384   // 128*128 low-res pixels
#define HWIN 65536   // 256*256 segmap pixels
#define OUT  512
#define PBLK 16      // mask_pack blocks per batch
#define MSBLK 128    // masked_sum blocks per batch (= F)

// ---------------- Kernel A: pack segment masks + per-block partial counts --
// grid = B*PBLK, 256 threads; thread packs 4 low-res pixels into one uchar4
// (bit s = segment-s membership). Per-block counts -> pcounts[block][s].
// Also zeroes the per-batch ready counters used by kernel B (stream-ordered).
__global__ __launch_bounds__(256) void mask_pack_kernel(
    const int* __restrict__ segmap,
    unsigned char* __restrict__ pmask,
    int* __restrict__ pcounts,
    unsigned int* __restrict__ ready) {
    const int b   = blockIdx.x >> 4;
    const int t   = threadIdx.x;
    if ((blockIdx.x & 15) == 0 && t == 0)
        atomicExch(&ready[b], 0u);            // device-scope, bypasses L1

    const int pbase = (blockIdx.x & 15) * 1024 + t * 4;  // 4 px, same row
    const int y = pbase >> 7;
    const int x = pbase & 127;
    const int* sm = segmap + (size_t)b * (S * HWIN);
    const int row = (2 * y) * 256 + 2 * x;    // 32B-aligned -> int4 ok

    unsigned char outb[4] = {0, 0, 0, 0};
    int cnt[S];
#pragma unroll
    for (int s = 0; s < S; ++s) {
        const int4 l0 = *(const int4*)(sm + s * HWIN + row);
        const int4 l1 = *(const int4*)(sm + s * HWIN + row + 4);
        int c = 0;
        if (l0.x) { outb[0] |= (1 << s); c++; }
        if (l0.z) { outb[1] |= (1 << s); c++; }
        if (l1.x) { outb[2] |= (1 << s); c++; }
        if (l1.z) { outb[3] |= (1 << s); c++; }
        cnt[s] = c;
    }
    *(uchar4*)(pmask + (size_t)b * HW + pbase) =
        make_uchar4(outb[0], outb[1], outb[2], outb[3]);

    __shared__ int sc[4][S];
#pragma unroll
    for (int s = 0; s < S; ++s) {
#pragma unroll
        for (int off = 32; off > 0; off >>= 1)
            cnt[s] += __shfl_down(cnt[s], off);
    }
    const int wave = t >> 6;
    if ((t & 63) == 0) {
#pragma unroll
        for (int s = 0; s < S; ++s) sc[wave][s] = cnt[s];
    }
    __syncthreads();
    if (t < S)
        pcounts[blockIdx.x * S + t] = sc[0][t] + sc[1][t] + sc[2][t] + sc[3][t];
}

// ---------------- Kernel B: masked segment sums + fused FC epilogue --------
// grid = B*F = 2048 blocks, 256 threads. Block (b,f) streams the 64 KiB plane
// codes[b,f,:,:]; writes sums[(b*S+s)*F+f]. The LAST finishing block of each
// batch (per-batch ready counter) computes out[b,s,:] = feats @ W^T + bias.
__global__ __launch_bounds__(256) void masked_sum_fc_kernel(
    const float* __restrict__ codes,
    const unsigned char* __restrict__ pmask,
    float* __restrict__ sums,
    const int* __restrict__ pcounts,
    unsigned int* __restrict__ ready,
    const float* __restrict__ fc_w,
    const float* __restrict__ fc_b,
    float* __restrict__ out) {
    const int bf = blockIdx.x;
    const int b  = bf >> 7;
    const int t  = threadIdx.x;
    const float4* cp = (const float4*)(codes + (size_t)bf * HW);
    const uchar4* mp = (const uchar4*)(pmask + (size_t)b * HW);

    float a0 = 0.f, a1 = 0.f, a2 = 0.f, a3 = 0.f;
#pragma unroll
    for (int i = 0; i < 4; ++i) {
        const int idx = i * 1024 + t;
        const float4 c0 = cp[idx];
        const float4 c1 = cp[idx + 256];
        const float4 c2 = cp[idx + 512];
        const float4 c3 = cp[idx + 768];
        const uchar4 m0 = mp[idx];
        const uchar4 m1 = mp[idx + 256];
        const uchar4 m2 = mp[idx + 512];
        const uchar4 m3 = mp[idx + 768];
#define ACC(mm, cc)                                \
        {                                          \
            a0 += ((mm) & 1) ? (cc) : 0.f;         \
            a1 += ((mm) & 2) ? (cc) : 0.f;         \
            a2 += ((mm) & 4) ? (cc) : 0.f;         \
            a3 += ((mm) & 8) ? (cc) : 0.f;         \
        }
        ACC(m0.x, c0.x); ACC(m0.y, c0.y); ACC(m0.z, c0.z); ACC(m0.w, c0.w);
        ACC(m1.x, c1.x); ACC(m1.y, c1.y); ACC(m1.z, c1.z); ACC(m1.w, c1.w);
        ACC(m2.x, c2.x); ACC(m2.y, c2.y); ACC(m2.z, c2.z); ACC(m2.w, c2.w);
        ACC(m3.x, c3.x); ACC(m3.y, c3.y); ACC(m3.z, c3.z); ACC(m3.w, c3.w);
#undef ACC
    }
#pragma unroll
    for (int off = 32; off > 0; off >>= 1) {
        a0 += __shfl_down(a0, off);
        a1 += __shfl_down(a1, off);
        a2 += __shfl_down(a2, off);
        a3 += __shfl_down(a3, off);
    }
    __shared__ float part[4][S];
    const int wave = t >> 6;
    if ((t & 63) == 0) {
        part[wave][0] = a0; part[wave][1] = a1;
        part[wave][2] = a2; part[wave][3] = a3;
    }
    __syncthreads();
    if (t < S) {
        const int f = bf & 127;
        sums[(size_t)(b * S + t) * F + f] =
            part[0][t] + part[1][t] + part[2][t] + part[3][t];
    }

    // ---- last-block-per-batch FC epilogue (release/acquire via ready[b]) ----
    __shared__ int amLast;
    if (t == 0) {
        __threadfence();                               // release sums
        const unsigned int old = atomicAdd(&ready[b], 1u);
        amLast = (old == MSBLK - 1);
    }
    __syncthreads();
    if (!amLast) return;
    __threadfence();                                   // acquire sums

    __shared__ float feats[S][F];
    __shared__ float sinv[S];
    if (t < S) {
        int c = 0;
#pragma unroll
        for (int blk = 0; blk < PBLK; ++blk)
            c += pcounts[(b * PBLK + blk) * S + t];
        sinv[t] = (c > 0) ? (1.0f / (float)c) : 0.0f;
    }
    __syncthreads();
    if (t < F) {
#pragma unroll
        for (int s = 0; s < S; ++s)
            feats[s][t] = sums[(size_t)(b * S + s) * F + t] * sinv[s];
    }
    __syncthreads();

    // thread t computes outputs o = t and o = t+256 for all 4 segments
    const float4* w0 = (const float4*)(fc_w + (size_t)t * F);
    const float4* w1 = (const float4*)(fc_w + (size_t)(t + 256) * F);
    float acc0[S], acc1[S];
#pragma unroll
    for (int s = 0; s < S; ++s) { acc0[s] = fc_b[t]; acc1[s] = fc_b[t + 256]; }
#pragma unroll
    for (int i = 0; i < F / 4; ++i) {
        const float4 wa = w0[i];
        const float4 wb = w1[i];
#pragma unroll
        for (int s = 0; s < S; ++s) {
            const float4 fv = ((const float4*)feats[s])[i];  // LDS broadcast
            acc0[s] += fv.x * wa.x + fv.y * wa.y + fv.z * wa.z + fv.w * wa.w;
            acc1[s] += fv.x * wb.x + fv.y * wb.y + fv.z * wb.z + fv.w * wb.w;
        }
    }
#pragma unroll
    for (int s = 0; s < S; ++s) {
        float* orow = out + (size_t)(b * S + s) * OUT;
        orow[t]       = acc0[s];
        orow[t + 256] = acc1[s];
    }
}

extern "C" void kernel_launch(void* const* d_in, const int* in_sizes, int n_in,
                              void* d_out, int out_size, void* d_ws, size_t ws_size,
                              hipStream_t stream) {
    const float* codes  = (const float*)d_in[0];
    const int*   segmap = (const int*)d_in[1];
    const float* fc_w   = (const float*)d_in[2];
    const float* fc_b   = (const float*)d_in[3];
    float* out = (float*)d_out;

    // ws layout: [pmask 256 KiB][pcounts 4 KiB][ready 64 B][pad][sums 32 KiB]
    unsigned char* pmask   = (unsigned char*)d_ws;
    int*           pcounts = (int*)((char*)d_ws + (size_t)B * HW);
    unsigned int*  ready   = (unsigned int*)((char*)pcounts + B * PBLK * S * 4);
    float*         sums    = (float*)((char*)ready + 256);

    mask_pack_kernel<<<B * PBLK, 256, 0, stream>>>(segmap, pmask, pcounts, ready);
    masked_sum_fc_kernel<<<B * MSBLK, 256, 0, stream>>>(
        codes, pmask, sums, pcounts, ready, fc_w, fc_b, out);
}

// Round 5
// 216.318 us; speedup vs baseline: 1.7428x; 1.7428x over previous
//
#include <hip/hip_runtime.h>

// Problem constants: codes [16,128,128,128] f32, segmap [16,4,1,256,256] i32,
// fc_w [512,128] f32, fc_b [512] f32.  Nearest 256->128 == sample (2y,2x).
//
// R3 lesson: per-block __threadfence (agent scope) on gfx950 costs ~200us
//   (L2 writeback per block across 8 XCDs) — last-block fusion abandoned.
// R4 lesson: 3->2 dispatch fusion bought only ~2us but introduced an
//   unresolved post-timing divergence — abandoned. This is the proven R2
//   structure: 3 kernels, no atomics on the data path, no fences.
#define B    16
#define S    4
#define F    128
#define HW   16384   // 128*128 low-res pixels
#define HWIN 65536   // 256*256 segmap pixels
#define OUT  512
#define PBLK 16      // mask_pack blocks per batch

// ---------------- Kernel 0: pack segment masks + per-block partial counts --
// grid = B*PBLK, 256 threads; thread packs 4 low-res pixels into one uchar4
// (bit s = segment-s membership). Per-block counts -> pcounts[block][s]
// (no global atomics, no memset needed).
__global__ __launch_bounds__(256) void mask_pack_kernel(
    const int* __restrict__ segmap,
    unsigned char* __restrict__ pmask,
    int* __restrict__ pcounts) {
    const int b   = blockIdx.x >> 4;
    const int t   = threadIdx.x;
    const int pbase = (blockIdx.x & 15) * 1024 + t * 4;  // 4 px, same row
    const int y = pbase >> 7;
    const int x = pbase & 127;
    const int* sm = segmap + (size_t)b * (S * HWIN);
    const int row = (2 * y) * 256 + 2 * x;   // 32B-aligned -> int4 ok

    unsigned char outb[4] = {0, 0, 0, 0};
    int cnt[S];
#pragma unroll
    for (int s = 0; s < S; ++s) {
        const int4 l0 = *(const int4*)(sm + s * HWIN + row);
        const int4 l1 = *(const int4*)(sm + s * HWIN + row + 4);
        int c = 0;
        if (l0.x) { outb[0] |= (1 << s); c++; }
        if (l0.z) { outb[1] |= (1 << s); c++; }
        if (l1.x) { outb[2] |= (1 << s); c++; }
        if (l1.z) { outb[3] |= (1 << s); c++; }
        cnt[s] = c;
    }
    *(uchar4*)(pmask + (size_t)b * HW + pbase) =
        make_uchar4(outb[0], outb[1], outb[2], outb[3]);

    // block-reduce the 4 counts: wave shuffle, then LDS across 4 waves
    __shared__ int sc[4][S];
#pragma unroll
    for (int s = 0; s < S; ++s) {
#pragma unroll
        for (int off = 32; off > 0; off >>= 1)
            cnt[s] += __shfl_down(cnt[s], off);
    }
    const int wave = t >> 6;
    if ((t & 63) == 0) {
#pragma unroll
        for (int s = 0; s < S; ++s) sc[wave][s] = cnt[s];
    }
    __syncthreads();
    if (t < S)
        pcounts[blockIdx.x * S + t] = sc[0][t] + sc[1][t] + sc[2][t] + sc[3][t];
}

// ---------------- Kernel 1: masked segment sums (the 128 MiB pass) ---------
// grid = B*F = 2048 blocks, 256 threads. Block (b,f) streams the 64 KiB plane
// codes[b,f,:,:] as 2x float4/iter + packed mask as uchar4; 4 running sums.
__global__ __launch_bounds__(256) void masked_sum_kernel(
    const float* __restrict__ codes,
    const unsigned char* __restrict__ pmask,
    float* __restrict__ sums) {
    const int bf = blockIdx.x;
    const int b  = bf >> 7;
    const int t  = threadIdx.x;
    const float4* cp = (const float4*)(codes + (size_t)bf * HW);
    const uchar4* mp = (const uchar4*)(pmask + (size_t)b * HW);

    float a0 = 0.f, a1 = 0.f, a2 = 0.f, a3 = 0.f;
#pragma unroll
    for (int i = 0; i < 8; ++i) {
        const int idx = i * 512 + t;
        const float4 c0 = cp[idx];
        const float4 c1 = cp[idx + 256];
        const uchar4 m0 = mp[idx];
        const uchar4 m1 = mp[idx + 256];
#define ACC(mm, cc)                                \
        {                                          \
            a0 += ((mm) & 1) ? (cc) : 0.f;         \
            a1 += ((mm) & 2) ? (cc) : 0.f;         \
            a2 += ((mm) & 4) ? (cc) : 0.f;         \
            a3 += ((mm) & 8) ? (cc) : 0.f;         \
        }
        ACC(m0.x, c0.x); ACC(m0.y, c0.y); ACC(m0.z, c0.z); ACC(m0.w, c0.w);
        ACC(m1.x, c1.x); ACC(m1.y, c1.y); ACC(m1.z, c1.z); ACC(m1.w, c1.w);
#undef ACC
    }
#pragma unroll
    for (int off = 32; off > 0; off >>= 1) {
        a0 += __shfl_down(a0, off);
        a1 += __shfl_down(a1, off);
        a2 += __shfl_down(a2, off);
        a3 += __shfl_down(a3, off);
    }
    __shared__ float part[4][S];
    const int wave = t >> 6;
    if ((t & 63) == 0) {
        part[wave][0] = a0; part[wave][1] = a1;
        part[wave][2] = a2; part[wave][3] = a3;
    }
    __syncthreads();
    if (t < S) {
        const int f = bf & 127;
        sums[(size_t)(b * S + t) * F + f] =
            part[0][t] + part[1][t] + part[2][t] + part[3][t];
    }
}

// ---------------- Kernel 2: counts finalize + feats @ W^T + b --------------
// grid = B*S = 64 blocks, 512 threads (one output element each).
__global__ __launch_bounds__(512) void fc_kernel(
    const float* __restrict__ sums,
    const int* __restrict__ pcounts,
    const float* __restrict__ fc_w,
    const float* __restrict__ fc_b,
    float* __restrict__ out) {
    const int bs = blockIdx.x;          // = b*S + s
    const int b  = bs >> 2;
    const int s  = bs & 3;
    const int t  = threadIdx.x;
    __shared__ float feats[F];
    __shared__ float sinv;
    if (t == 0) {
        int c = 0;
#pragma unroll
        for (int blk = 0; blk < PBLK; ++blk)
            c += pcounts[(b * PBLK + blk) * S + s];
        sinv = (c > 0) ? (1.0f / (float)c) : 0.0f;
    }
    __syncthreads();
    if (t < F) feats[t] = sums[(size_t)bs * F + t] * sinv;
    __syncthreads();

    const float4* w4 = (const float4*)(fc_w + (size_t)t * F);
    const float4* f4 = (const float4*)feats;
    float acc = fc_b[t];
#pragma unroll
    for (int i = 0; i < F / 4; ++i) {
        const float4 wv = w4[i];
        const float4 fv = f4[i];
        acc += fv.x * wv.x + fv.y * wv.y + fv.z * wv.z + fv.w * wv.w;
    }
    out[(size_t)bs * OUT + t] = acc;
}

extern "C" void kernel_launch(void* const* d_in, const int* in_sizes, int n_in,
                              void* d_out, int out_size, void* d_ws, size_t ws_size,
                              hipStream_t stream) {
    const float* codes  = (const float*)d_in[0];
    const int*   segmap = (const int*)d_in[1];
    const float* fc_w   = (const float*)d_in[2];
    const float* fc_b   = (const float*)d_in[3];
    float* out = (float*)d_out;

    // ws layout: [pmask 256 KiB][pcounts 4 KiB][sums 32 KiB]
    unsigned char* pmask   = (unsigned char*)d_ws;
    int*           pcounts = (int*)((char*)d_ws + (size_t)B * HW);
    float*         sums    = (float*)((char*)d_ws + (size_t)B * HW + B * PBLK * S * 4);

    mask_pack_kernel<<<B * PBLK, 256, 0, stream>>>(segmap, pmask, pcounts);
    masked_sum_kernel<<<B * F, 256, 0, stream>>>(codes, pmask, sums);
    fc_kernel<<<B * S, OUT, 0, stream>>>(sums, pcounts, fc_w, fc_b, out);
}